// Round 1
// baseline (174.818 us; speedup 1.0000x reference)
//
#include <hip/hip_runtime.h>
#include <hip/hip_bf16.h>

#define B_  2
#define T_  2048
#define D_  1024
#define H_  16
#define KH_ 4
#define DH_ 64

typedef __attribute__((ext_vector_type(8))) short bf16x8;   // 8 bf16 = 4 VGPRs
typedef __attribute__((ext_vector_type(4))) float f32x4;

// log2(e)/8: folded into Q at projection time so softmax is p = exp2(s_raw).
#define QSCALE 0.18033688011112043f

// single-instruction v_exp_f32 if available (OCML exp2f is ~10 instrs)
#if defined(__has_builtin)
#  if __has_builtin(__builtin_amdgcn_exp2f)
#    define EXP2F(x) __builtin_amdgcn_exp2f(x)
#  endif
#endif
#ifndef EXP2F
#  define EXP2F(x) exp2f(x)
#endif

// fp32 -> bf16 RNE (scalar, for prep paths where cvt_pk doesn't fit)
__device__ __forceinline__ unsigned short f2bf(float f) {
  union { float f; unsigned int u; } v; v.f = f;
  return (unsigned short)((v.u + 0x7FFFu + ((v.u >> 16) & 1u)) >> 16);
}
// packed fp32x2 -> bf16x2 via v_cvt_pk_bf16_f32 (1 VALU op)
__device__ __forceinline__ unsigned int pk2(float a, float b) {
  union { __hip_bfloat162 h2; unsigned int u; } v;
  v.h2 = __float22bfloat162_rn(make_float2(a, b));
  return v.u;
}

// async global->LDS, 16B per lane. LDS dest = wave-uniform base + lane*16;
// global source is per-lane (pre-swizzled source pattern, m173/rule #21).
__device__ __forceinline__ void g2l16(const void* g, void* l) {
  __builtin_amdgcn_global_load_lds(
      (const __attribute__((address_space(1))) void*)g,
      (__attribute__((address_space(3))) void*)l, 16, 0, 0);
}

// d-slot permutation: slot(d) = (d&15)*4 + (d>>4). Applied consistently to
// Q/K d-dims (QK contraction invariant), V key-dim (matches P slot layout),
// att per-head d-dim + WoT k-rows (outproj contraction invariant). Exact.

// ---------------------------------------------------------------------------
// Merged prep (one launch): x->bf16, Wqkv->WT (bf16 transposed),
// Wo->WoT (bf16 transposed, k-rows sigma-permuted per head), RoPE table.
// ---------------------------------------------------------------------------
__global__ __launch_bounds__(256) void prep_kernel(
    const float* __restrict__ x,  const float* __restrict__ Wq,
    const float* __restrict__ Wk, const float* __restrict__ Wv,
    const float* __restrict__ Wo,
    short* __restrict__ xb, short* __restrict__ WT, short* __restrict__ WoT,
    float2* __restrict__ tbl) {
  __shared__ short Ts[64 * 72];
  const int bid = blockIdx.x, tid = threadIdx.x;

  if (bid < 2048) {                             // ---- x -> bf16
    const size_t i8 = ((size_t)bid * 256 + tid) * 8;
    const float4 a = *(const float4*)&x[i8];
    const float4 b = *(const float4*)&x[i8 + 4];
    uint4 p; p.x = pk2(a.x, a.y); p.y = pk2(a.z, a.w);
    p.z = pk2(b.x, b.y); p.w = pk2(b.z, b.w);
    *(uint4*)&xb[i8] = p;
  } else if (bid < 2688) {                      // ---- WT / WoT transpose
    const bool isW = bid < 2432;
    const int idx = isW ? (bid - 2048) : (bid - 2432);
    const int n0 = (idx >> 4) * 64, k0 = (idx & 15) * 64;
    const float* src; int ncols, c0; short* dst;
    if (isW) {
      dst = WT;
      if (n0 < 1024)      { src = Wq; ncols = 1024; c0 = n0; }
      else if (n0 < 1280) { src = Wk; ncols = 256;  c0 = n0 - 1024; }
      else                { src = Wv; ncols = 256;  c0 = n0 - 1280; }
    } else { dst = WoT; src = Wo; ncols = 1024; c0 = n0; }
    for (int i = tid; i < 1024; i += 256) {
      const int kr = i >> 4, c4 = (i & 15) << 2;
      // WoT k-rows permuted: slot(kr) = (kr&15)*4 + (kr>>4) (k0 is 64-aligned
      // = one head's range, so per-head sigma).
      const int kc = isW ? kr : ((kr & 15) * 4 + (kr >> 4));
      const float4 w = *(const float4*)&src[(size_t)(k0 + kr) * ncols + c0 + c4];
      Ts[(c4 + 0) * 72 + kc] = (short)f2bf(w.x);
      Ts[(c4 + 1) * 72 + kc] = (short)f2bf(w.y);
      Ts[(c4 + 2) * 72 + kc] = (short)f2bf(w.z);
      Ts[(c4 + 3) * 72 + kc] = (short)f2bf(w.w);
    }
    __syncthreads();
    for (int c = tid; c < 512; c += 256) {
      const int nr = c >> 3, c8 = (c & 7) * 8;
      *(bf16x8*)&dst[(size_t)(n0 + nr) * 1024 + k0 + c8] =
          *(const bf16x8*)&Ts[nr * 72 + c8];
    }
  } else {                                      // ---- RoPE table
    const int e = (bid - 2688) * 256 + tid;     // 65536 entries
    const int t = e >> 5, i2 = e & 31;
    const float freq = exp2f(-(float)(2 * i2) * (18.931568569324174f / 64.0f));
    float sn, cs; sincosf((float)t * freq, &sn, &cs);
    tbl[e] = make_float2(cs, sn);
  }
}

// ---------------------------------------------------------------------------
// Kernel 1: QKV projection, 128x64 tiles, BK=128 (8 k-iters, 32 MFMA per
// barrier-pair per wave), grid (32,24) = 768 blocks (3/CU).
// Staging via global_load_lds width=16 (m97 pattern: single-buffered,
// 2 barriers + vmcnt(0) drain per K-step; no VGPR round-trip).
// LDS linear stride 128 (required by global_load_lds) with XOR block swizzle:
// LDS[row][cb] holds global block cb^(row&7); ds_read re-applies the XOR.
// Keeps fragment reads <=2-way bank aliased (free, m136).
// nt<16: Q (RoPE + QSCALE fold). 16..19: K (RoPE). 20..23: V (LDS-bounce
// transpose -> (b,kh,d,t), key slots permuted). LDS 48 KB -> 3 blocks/CU.
// ---------------------------------------------------------------------------
__global__ __launch_bounds__(256) void qkv_mfma_kernel(
    const short* __restrict__ xb, const short* __restrict__ WT,
    const float2* __restrict__ tbl,
    short* __restrict__ qo, short* __restrict__ ko, short* __restrict__ vt) {
  __shared__ short Xs[128 * 128];
  __shared__ short Wt[64 * 128];
  const int tid = threadIdx.x;
  const int lane = tid & 63, w = tid >> 6;
  const int lm = lane & 15, quad = lane >> 4;
  const int lr = lane >> 4;                     // row within 4-row LDS chunk
  const int lb = lane & 15;                     // dest 16B block within row
  const int m0 = blockIdx.x * 128;
  const int n0 = blockIdx.y * 64;               // 0..1535

  f32x4 acc[2][4];
  #pragma unroll
  for (int sm = 0; sm < 2; ++sm)
    #pragma unroll
    for (int ct = 0; ct < 4; ++ct) acc[sm][ct] = (f32x4){0.f, 0.f, 0.f, 0.f};

  for (int kt = 0; kt < 8; ++kt) {
    __syncthreads();                            // prior tile's LDS reads done
    #pragma unroll
    for (int u = 0; u < 8; ++u) {               // Xs chunk w*8+u (4 rows/1KB)
      const int r = (w * 8 + u) * 4 + lr;
      const int sb = lb ^ (r & 7);              // inverse-swizzled source blk
      g2l16(&xb[(size_t)(m0 + r) * 1024 + kt * 128 + sb * 8],
            &Xs[(w * 8 + u) * 512]);
    }
    #pragma unroll
    for (int u = 0; u < 4; ++u) {               // Wt chunk w*4+u
      const int r = (w * 4 + u) * 4 + lr;
      const int sb = lb ^ (r & 7);
      g2l16(&WT[(size_t)(n0 + r) * 1024 + kt * 128 + sb * 8],
            &Wt[(w * 4 + u) * 512]);
    }
    asm volatile("s_waitcnt vmcnt(0)" ::: "memory");
    __syncthreads();                            // staged tile visible
    #pragma unroll
    for (int s = 0; s < 4; ++s) {               // 4 k-steps of 32
      bf16x8 bfr[4];
      #pragma unroll
      for (int ct = 0; ct < 4; ++ct)
        bfr[ct] = *(const bf16x8*)&Wt[(ct * 16 + lm) * 128 +
                                      (((s * 4 + quad) ^ (lm & 7)) << 3)];
      #pragma unroll
      for (int sm = 0; sm < 2; ++sm) {
        const bf16x8 a = *(const bf16x8*)&Xs[(w * 32 + sm * 16 + lm) * 128 +
                                             (((s * 4 + quad) ^ (lm & 7)) << 3)];
        #pragma unroll
        for (int ct = 0; ct < 4; ++ct)
          acc[sm][ct] =
              __builtin_amdgcn_mfma_f32_16x16x32_bf16(a, bfr[ct], acc[sm][ct], 0, 0, 0);
      }
    }
  }

  if (n0 < 1280) {                              // ---- Q or K: RoPE + b64 store
    const bool isQ = n0 < 1024;
    short* outp = isQ ? qo : ko;
    const int base = isQ ? n0 : n0 - 1024;
    const int nh = isQ ? H_ : KH_;
    const int hh = base >> 6;                   // tile width 64 = one head
    const float post = isQ ? QSCALE : 1.0f;     // fold softmax scale into Q
    #pragma unroll
    for (int sm = 0; sm < 2; ++sm)
      #pragma unroll
      for (int r = 0; r < 4; ++r) {
        const int row = m0 + w * 32 + sm * 16 + quad * 4 + r;
        const int b = row >> 11, t = row & 2047;
        float v4[4];
        #pragma unroll
        for (int ct = 0; ct < 4; ++ct) {
          float val = acc[sm][ct][r];
          const float other = __shfl_xor(val, 1);
          const int ci = ct * 16 + lm;          // d within head
          const float2 cs = tbl[t * 32 + (ci >> 1)];
          val = ((ci & 1) == 0) ? (val * cs.x - other * cs.y)
                                : (val * cs.x + other * cs.y);
          v4[ct] = val * post;
        }
        // d ct*16+lm -> slot lm*4+ct: one b64 store of 4 consecutive slots
        uint2 st; st.x = pk2(v4[0], v4[1]); st.y = pk2(v4[2], v4[3]);
        *(uint2*)&outp[((size_t)(b * nh + hh) * T_ + t) * DH_ + lm * 4] = st;
      }
  } else {                                      // ---- V: LDS-bounce transpose
    __syncthreads();                            // done with Xs as GEMM tile
    #pragma unroll
    for (int sm = 0; sm < 2; ++sm)
      #pragma unroll
      for (int r = 0; r < 4; ++r)
        #pragma unroll
        for (int ct = 0; ct < 4; ++ct)
          Xs[(w * 32 + sm * 16 + quad * 4 + r) * 72 + ct * 16 + lm] =
              (short)f2bf(acc[sm][ct][r]);      // Xs[t][d], stride 72 region
    __syncthreads();
    const int kh = (n0 - 1280) >> 6;
    const int b = m0 >> 11, t0 = m0 & 2047;
    short* vb = vt + (size_t)(b * KH_ + kh) * DH_ * T_;
    for (int c = tid; c < 1024; c += 256) {     // 64 d-rows x 16 chunks of 8 slots
      const int d = c >> 4, c8 = (c & 15) * 8;
      short tmp[8];
      #pragma unroll
      for (int j = 0; j < 8; ++j) {
        const int s = c8 + j, sg = s & 63;      // slot s -> token within group
        const int tok = (s & 64) + ((sg & 3) << 4) + (sg >> 2);
        tmp[j] = Xs[tok * 72 + d];
      }
      *(bf16x8*)&vb[(size_t)d * T_ + t0 + c8] = *(bf16x8*)tmp;
    }
  }
}

// ---------------------------------------------------------------------------
// Kernel 2: causal flash attention. Grid = 1024 1-D blocks, ONE q-tile each
// (qt = 31 - bx>>5: heavy tiles dispatch first so the tail is the 1-step
// tiles). Qs LDS dropped: each lane's kt-invariant Q fragment is a direct
// global b128 load -> LDS 54272 B = 3 blocks/CU (was 2). Peeled K-loop:
// main loop is a full 128-key pair (j=0 never diagonal; j=1 diagonal only
// on its last iteration); odd final step peeled. Ps double-buffered so the
// unrolled pair has no cross-step LDS deps. v_exp_f32 softmax (scale folded
// into Q). P at permuted slot lm*4+ct (b64 writes); V^T in matching slot
// order; row-sum via MFMA ones-column; register prefetch for K/V.
// s_setprio(1) around both MFMA clusters (T5: +4-7% on attn, m191).
// ---------------------------------------------------------------------------
__global__ __launch_bounds__(256) void attn_mfma_kernel(
    const short* __restrict__ q, const short* __restrict__ k,
    const short* __restrict__ vt, short* __restrict__ att) {
  __shared__ short Ks[128 * 72];
  __shared__ short Vts[64 * 136];               // [d][slot 0..127]
  __shared__ short Ps0[64 * 72];                // [q][slot] (j=0)
  __shared__ short Ps1[64 * 72];                // [q][slot] (j=1)

  const int bx = blockIdx.x;
  const int qt = 31 - (bx >> 5);                // heavy-first dispatch
  const int hb = bx & 31;
  const int h = hb >> 1, b = hb & 1;
  const int kh = h >> 2;                        // n_rep = 4
  const int tid = threadIdx.x;
  const int lane = tid & 63, w = tid >> 6;
  const int lm = lane & 15, quad = lane >> 4;
  const int q0 = qt * 64;

  const short* qb = q + (size_t)(b * H_ + h) * T_ * DH_;
  const short* kb = k + (size_t)(b * KH_ + kh) * T_ * DH_;
  const short* vb = vt + (size_t)(b * KH_ + kh) * DH_ * T_;

  bf16x8 ones;
  #pragma unroll
  for (int i = 0; i < 8; ++i) ones[i] = (short)0x3F80;  // bf16 1.0

  bf16x8 aq[2];                                 // kt-invariant Q fragments
  #pragma unroll
  for (int s = 0; s < 2; ++s)                   // direct global load (no LDS)
    aq[s] = *(const bf16x8*)&qb[(size_t)(q0 + w * 16 + lm) * 64 + s * 32 + quad * 8];

  bf16x8 pk[4], pv[4];
  #pragma unroll
  for (int u = 0; u < 4; ++u) {                 // preload r2=0 (128 keys)
    const int c = tid + u * 256;
    const int row = c >> 3, c8 = (c & 7) * 8;
    pk[u] = *(const bf16x8*)&kb[(size_t)row * 64 + c8];
    const int d = c >> 4, c16 = (c & 15) * 8;
    pv[u] = *(const bf16x8*)&vb[(size_t)d * T_ + c16];
  }

  f32x4 oacc[4], lacc;
  #pragma unroll
  for (int i = 0; i < 4; ++i) oacc[i] = (f32x4){0.f, 0.f, 0.f, 0.f};
  lacc = (f32x4){0.f, 0.f, 0.f, 0.f};

  // one 64-key tile-step (j selects which staged half; diag wave-uniform)
  auto step = [&](int j, bool diag, short* Ps) {
    f32x4 sacc[4];
    #pragma unroll
    for (int i = 0; i < 4; ++i) sacc[i] = (f32x4){0.f, 0.f, 0.f, 0.f};
    __builtin_amdgcn_s_setprio(1);
    #pragma unroll
    for (int s = 0; s < 2; ++s) {
      #pragma unroll
      for (int ct = 0; ct < 4; ++ct) {
        const bf16x8 bb =
            *(const bf16x8*)&Ks[(j * 64 + ct * 16 + lm) * 72 + s * 32 + quad * 8];
        sacc[ct] = __builtin_amdgcn_mfma_f32_16x16x32_bf16(aq[s], bb, sacc[ct], 0, 0, 0);
      }
    }
    __builtin_amdgcn_s_setprio(0);
    if (diag) {
      #pragma unroll
      for (int r = 0; r < 4; ++r) {
        const int qi = w * 16 + quad * 4 + r;
        float p[4];
        #pragma unroll
        for (int ct = 0; ct < 4; ++ct) {
          float pv2 = EXP2F(sacc[ct][r]);
          if ((ct * 16 + lm) > qi) pv2 = 0.f;  // causal mask
          p[ct] = pv2;
        }
        uint2 pw2; pw2.x = pk2(p[0], p[1]); pw2.y = pk2(p[2], p[3]);
        *(uint2*)&Ps[qi * 72 + lm * 4] = pw2;
      }
    } else {
      #pragma unroll
      for (int r = 0; r < 4; ++r) {
        const int qi = w * 16 + quad * 4 + r;
        uint2 pw2;
        pw2.x = pk2(EXP2F(sacc[0][r]), EXP2F(sacc[1][r]));
        pw2.y = pk2(EXP2F(sacc[2][r]), EXP2F(sacc[3][r]));
        *(uint2*)&Ps[qi * 72 + lm * 4] = pw2;
      }
    }
    // P wave-private: no barrier.
    __builtin_amdgcn_s_setprio(1);
    #pragma unroll
    for (int s = 0; s < 2; ++s) {
      const bf16x8 pa = *(const bf16x8*)&Ps[(w * 16 + lm) * 72 + s * 32 + quad * 8];
      lacc = __builtin_amdgcn_mfma_f32_16x16x32_bf16(pa, ones, lacc, 0, 0, 0);
      #pragma unroll
      for (int ct = 0; ct < 4; ++ct) {
        const bf16x8 vfr = *(const bf16x8*)&Vts[(ct * 16 + lm) * 136 +
                                                j * 64 + s * 32 + quad * 8];
        oacc[ct] = __builtin_amdgcn_mfma_f32_16x16x32_bf16(pa, vfr, oacc[ct], 0, 0, 0);
      }
    }
    __builtin_amdgcn_s_setprio(0);
  };

  auto stage = [&](int r2) {
    __syncthreads();                            // prior K/V LDS reads done
    #pragma unroll
    for (int u = 0; u < 4; ++u) {
      const int c = tid + u * 256;
      const int row = c >> 3, c8 = (c & 7) * 8;
      *(bf16x8*)&Ks[row * 72 + c8] = pk[u];
      const int d = c >> 4, c16 = (c & 15) * 8;
      *(bf16x8*)&Vts[d * 136 + c16] = pv[u];
    }
    __syncthreads();
    const int r2n = (r2 + 2 <= qt) ? (r2 + 2) : r2;   // prefetch next pair
    #pragma unroll
    for (int u = 0; u < 4; ++u) {
      const int c = tid + u * 256;
      const int row = c >> 3, c8 = (c & 7) * 8;
      pk[u] = *(const bf16x8*)&kb[(size_t)(r2n * 64 + row) * 64 + c8];
      const int d = c >> 4, c16 = (c & 15) * 8;
      pv[u] = *(const bf16x8*)&vb[(size_t)d * T_ + r2n * 64 + c16];
    }
  };

  int r2 = 0;
  for (; r2 + 1 <= qt; r2 += 2) {               // full pairs only
    stage(r2);
    step(0, false, Ps0);                        // never diagonal
    step(1, r2 + 1 == qt, Ps1);                 // diagonal only on last pair
  }
  if (r2 == qt) {                               // peeled final step (even qt)
    stage(r2);
    step(0, true, Ps0);
  }

  #pragma unroll
  for (int r = 0; r < 4; ++r) {
    const int qrow = q0 + w * 16 + quad * 4 + r;
    const float inv = 1.f / lacc[r];
    // d ct*16+lm -> slot lm*4+ct (WoT k-rows match): one b64 store
    uint2 st;
    st.x = pk2(oacc[0][r] * inv, oacc[1][r] * inv);
    st.y = pk2(oacc[2][r] * inv, oacc[3][r] * inv);
    *(uint2*)&att[((size_t)b * T_ + qrow) * 1024 + h * 64 + lm * 4] = st;
  }
}

// ---------------------------------------------------------------------------
// Kernel 3: output projection, 128x64 tiles, BK=128 (8 k-iters), grid
// (32,16) = 512 blocks. Same global_load_lds staging + XOR swizzle as
// kernel 1. bf16 in (slot-permuted k-dim, matched by WoT), fp32 out.
// ---------------------------------------------------------------------------
__global__ __launch_bounds__(256) void outproj_mfma_kernel(
    const short* __restrict__ att, const short* __restrict__ WoT,
    float* __restrict__ out) {
  __shared__ short Xs[128 * 128];
  __shared__ short Wt[64 * 128];
  const int tid = threadIdx.x;
  const int lane = tid & 63, w = tid >> 6;
  const int lm = lane & 15, quad = lane >> 4;
  const int lr = lane >> 4;
  const int lb = lane & 15;
  const int m0 = blockIdx.x * 128;
  const int n0 = blockIdx.y * 64;

  f32x4 acc[2][4];
  #pragma unroll
  for (int sm = 0; sm < 2; ++sm)
    #pragma unroll
    for (int ct = 0; ct < 4; ++ct) acc[sm][ct] = (f32x4){0.f, 0.f, 0.f, 0.f};

  for (int kt = 0; kt < 8; ++kt) {
    __syncthreads();
    #pragma unroll
    for (int u = 0; u < 8; ++u) {
      const int r = (w * 8 + u) * 4 + lr;
      const int sb = lb ^ (r & 7);
      g2l16(&att[(size_t)(m0 + r) * 1024 + kt * 128 + sb * 8],
            &Xs[(w * 8 + u) * 512]);
    }
    #pragma unroll
    for (int u = 0; u < 4; ++u) {
      const int r = (w * 4 + u) * 4 + lr;
      const int sb = lb ^ (r & 7);
      g2l16(&WoT[(size_t)(n0 + r) * 1024 + kt * 128 + sb * 8],
            &Wt[(w * 4 + u) * 512]);
    }
    asm volatile("s_waitcnt vmcnt(0)" ::: "memory");
    __syncthreads();
    #pragma unroll
    for (int s = 0; s < 4; ++s) {
      bf16x8 bfr[4];
      #pragma unroll
      for (int ct = 0; ct < 4; ++ct)
        bfr[ct] = *(const bf16x8*)&Wt[(ct * 16 + lm) * 128 +
                                      (((s * 4 + quad) ^ (lm & 7)) << 3)];
      #pragma unroll
      for (int sm = 0; sm < 2; ++sm) {
        const bf16x8 a = *(const bf16x8*)&Xs[(w * 32 + sm * 16 + lm) * 128 +
                                             (((s * 4 + quad) ^ (lm & 7)) << 3)];
        #pragma unroll
        for (int ct = 0; ct < 4; ++ct)
          acc[sm][ct] =
              __builtin_amdgcn_mfma_f32_16x16x32_bf16(a, bfr[ct], acc[sm][ct], 0, 0, 0);
      }
    }
  }

  #pragma unroll
  for (int sm = 0; sm < 2; ++sm)
    #pragma unroll
    for (int r = 0; r < 4; ++r) {
      const int row = m0 + w * 32 + sm * 16 + quad * 4 + r;
      #pragma unroll
      for (int ct = 0; ct < 4; ++ct)
        out[(size_t)row * 1024 + n0 + ct * 16 + lm] = acc[sm][ct][r];
    }
}

extern "C" void kernel_launch(void* const* d_in, const int* in_sizes, int n_in,
                              void* d_out, int out_size, void* d_ws, size_t ws_size,
                              hipStream_t stream) {
  const float* x  = (const float*)d_in[0];
  // d_in[1] = mask: fixed causal tril, handled analytically; never read.
  const float* Wq = (const float*)d_in[2];
  const float* Wk = (const float*)d_in[3];
  const float* Wv = (const float*)d_in[4];
  const float* Wo = (const float*)d_in[5];
  float* out = (float*)d_out;

  // ws carve (bf16 shorts unless noted): xb 8.4MB | WT 3.1MB | WoT 2.1MB |
  // q 8.4MB | k 2.1MB | vt 2.1MB | att 8.4MB | rope tbl 0.5MB  ~= 35.1MB
  short* xb   = (short*)d_ws;
  short* WT   = xb  + (size_t)4194304;          // 1536*1024
  short* WoT  = WT  + (size_t)1572864;          // 1024*1024 (k sigma-permuted)
  short* qb   = WoT + (size_t)1048576;          // 2*16*2048*64 (d sigma-permuted)
  short* kb   = qb  + (size_t)4194304;          // 2*4*2048*64 (d sigma-permuted)
  short* vtb  = kb  + (size_t)1048576;          // 2*4*64*2048 (transposed+permuted)
  short* attb = vtb + (size_t)1048576;          // 2*2048*1024 (d sigma-permuted)
  float2* tbl = (float2*)(attb + (size_t)4194304);  // 2048*32 float2

  prep_kernel<<<dim3(2944), dim3(256), 0, stream>>>(
      x, Wq, Wk, Wv, Wo, xb, WT, WoT, tbl);
  qkv_mfma_kernel<<<dim3(32, 24), dim3(256), 0, stream>>>(xb, WT, tbl, qb, kb, vtb);
  attn_mfma_kernel<<<dim3(1024), dim3(256), 0, stream>>>(qb, kb, vtb, attb);
  outproj_mfma_kernel<<<dim3(32, 16), dim3(256), 0, stream>>>(attb, WoT, out);
}

// Round 2
// 169.569 us; speedup vs baseline: 1.0310x; 1.0310x over previous
//
#include <hip/hip_runtime.h>
#include <hip/hip_bf16.h>

#define B_  2
#define T_  2048
#define D_  1024
#define H_  16
#define KH_ 4
#define DH_ 64

typedef __attribute__((ext_vector_type(8))) short bf16x8;   // 8 bf16 = 4 VGPRs
typedef __attribute__((ext_vector_type(4))) float f32x4;

// log2(e)/8: folded into Q at projection time so softmax is p = exp2(s_raw).
#define QSCALE 0.18033688011112043f

// single-instruction v_exp_f32 if available (OCML exp2f is ~10 instrs)
#if defined(__has_builtin)
#  if __has_builtin(__builtin_amdgcn_exp2f)
#    define EXP2F(x) __builtin_amdgcn_exp2f(x)
#  endif
#endif
#ifndef EXP2F
#  define EXP2F(x) exp2f(x)
#endif

// fp32 -> bf16 RNE (scalar, for prep paths where cvt_pk doesn't fit)
__device__ __forceinline__ unsigned short f2bf(float f) {
  union { float f; unsigned int u; } v; v.f = f;
  return (unsigned short)((v.u + 0x7FFFu + ((v.u >> 16) & 1u)) >> 16);
}
// packed fp32x2 -> bf16x2 via v_cvt_pk_bf16_f32 (1 VALU op)
__device__ __forceinline__ unsigned int pk2(float a, float b) {
  union { __hip_bfloat162 h2; unsigned int u; } v;
  v.h2 = __float22bfloat162_rn(make_float2(a, b));
  return v.u;
}

// async global->LDS, 16B per lane. LDS dest = wave-uniform base + lane*16;
// global source is per-lane (pre-swizzled source pattern, m173/rule #21).
__device__ __forceinline__ void g2l16(const void* g, void* l) {
  __builtin_amdgcn_global_load_lds(
      (const __attribute__((address_space(1))) void*)g,
      (__attribute__((address_space(3))) void*)l, 16, 0, 0);
}

// d-slot permutation: slot(d) = (d&15)*4 + (d>>4). Applied consistently to
// Q/K d-dims (QK contraction invariant), att per-head d-dim + WoT k-rows
// (outproj contraction invariant). Exact.
//
// V key-slot permutation (attn swapped-QK in-register P): slot g (0..63)
// holds key tok(g) with bit map  tok5<-g5, tok4<-g2, tok3:2<-g4:3,
// tok1:0<-g1:0.  This makes the PV A-operand buildable from each lane's OWN
// exp'd QK outputs (no cross-lane exchange, no P LDS bounce):
//   A[q=lm][kcol=quad*8+2i'+e] = exp(sacc[2s+(i'>>1)][2(i'&1)+e])
// where sacc[ct][r] = P[key ct*16+quad*4+r][q=lm] from mfma(K,Q).

// ---------------------------------------------------------------------------
// Merged prep (one launch): x->bf16, Wqkv->WT (bf16 transposed),
// Wo->WoT (bf16 transposed, k-rows sigma-permuted per head), RoPE table.
// ---------------------------------------------------------------------------
__global__ __launch_bounds__(256) void prep_kernel(
    const float* __restrict__ x,  const float* __restrict__ Wq,
    const float* __restrict__ Wk, const float* __restrict__ Wv,
    const float* __restrict__ Wo,
    short* __restrict__ xb, short* __restrict__ WT, short* __restrict__ WoT,
    float2* __restrict__ tbl) {
  __shared__ short Ts[64 * 72];
  const int bid = blockIdx.x, tid = threadIdx.x;

  if (bid < 2048) {                             // ---- x -> bf16
    const size_t i8 = ((size_t)bid * 256 + tid) * 8;
    const float4 a = *(const float4*)&x[i8];
    const float4 b = *(const float4*)&x[i8 + 4];
    uint4 p; p.x = pk2(a.x, a.y); p.y = pk2(a.z, a.w);
    p.z = pk2(b.x, b.y); p.w = pk2(b.z, b.w);
    *(uint4*)&xb[i8] = p;
  } else if (bid < 2688) {                      // ---- WT / WoT transpose
    const bool isW = bid < 2432;
    const int idx = isW ? (bid - 2048) : (bid - 2432);
    const int n0 = (idx >> 4) * 64, k0 = (idx & 15) * 64;
    const float* src; int ncols, c0; short* dst;
    if (isW) {
      dst = WT;
      if (n0 < 1024)      { src = Wq; ncols = 1024; c0 = n0; }
      else if (n0 < 1280) { src = Wk; ncols = 256;  c0 = n0 - 1024; }
      else                { src = Wv; ncols = 256;  c0 = n0 - 1280; }
    } else { dst = WoT; src = Wo; ncols = 1024; c0 = n0; }
    for (int i = tid; i < 1024; i += 256) {
      const int kr = i >> 4, c4 = (i & 15) << 2;
      // WoT k-rows permuted: slot(kr) = (kr&15)*4 + (kr>>4) (k0 is 64-aligned
      // = one head's range, so per-head sigma).
      const int kc = isW ? kr : ((kr & 15) * 4 + (kr >> 4));
      const float4 w = *(const float4*)&src[(size_t)(k0 + kr) * ncols + c0 + c4];
      Ts[(c4 + 0) * 72 + kc] = (short)f2bf(w.x);
      Ts[(c4 + 1) * 72 + kc] = (short)f2bf(w.y);
      Ts[(c4 + 2) * 72 + kc] = (short)f2bf(w.z);
      Ts[(c4 + 3) * 72 + kc] = (short)f2bf(w.w);
    }
    __syncthreads();
    for (int c = tid; c < 512; c += 256) {
      const int nr = c >> 3, c8 = (c & 7) * 8;
      *(bf16x8*)&dst[(size_t)(n0 + nr) * 1024 + k0 + c8] =
          *(const bf16x8*)&Ts[nr * 72 + c8];
    }
  } else {                                      // ---- RoPE table
    const int e = (bid - 2688) * 256 + tid;     // 65536 entries
    const int t = e >> 5, i2 = e & 31;
    const float freq = exp2f(-(float)(2 * i2) * (18.931568569324174f / 64.0f));
    float sn, cs; sincosf((float)t * freq, &sn, &cs);
    tbl[e] = make_float2(cs, sn);
  }
}

// ---------------------------------------------------------------------------
// Kernel 1: QKV projection, 128x64 tiles, BK=128 (8 k-iters, 32 MFMA per
// barrier-pair per wave), grid (32,24) = 768 blocks (3/CU).
// Staging via global_load_lds width=16 (m97 pattern). LDS linear stride 128
// with XOR block swizzle (source-side pre-swizzle, rule #21).
// nt<16: Q (RoPE + QSCALE fold). 16..19: K (RoPE). 20..23: V (LDS-bounce
// transpose -> (b,kh,d,t), key slots permuted per attn's in-register-P map).
// ---------------------------------------------------------------------------
__global__ __launch_bounds__(256) void qkv_mfma_kernel(
    const short* __restrict__ xb, const short* __restrict__ WT,
    const float2* __restrict__ tbl,
    short* __restrict__ qo, short* __restrict__ ko, short* __restrict__ vt) {
  __shared__ short Xs[128 * 128];
  __shared__ short Wt[64 * 128];
  const int tid = threadIdx.x;
  const int lane = tid & 63, w = tid >> 6;
  const int lm = lane & 15, quad = lane >> 4;
  const int lr = lane >> 4;                     // row within 4-row LDS chunk
  const int lb = lane & 15;                     // dest 16B block within row
  const int m0 = blockIdx.x * 128;
  const int n0 = blockIdx.y * 64;               // 0..1535

  f32x4 acc[2][4];
  #pragma unroll
  for (int sm = 0; sm < 2; ++sm)
    #pragma unroll
    for (int ct = 0; ct < 4; ++ct) acc[sm][ct] = (f32x4){0.f, 0.f, 0.f, 0.f};

  for (int kt = 0; kt < 8; ++kt) {
    __syncthreads();                            // prior tile's LDS reads done
    #pragma unroll
    for (int u = 0; u < 8; ++u) {               // Xs chunk w*8+u (4 rows/1KB)
      const int r = (w * 8 + u) * 4 + lr;
      const int sb = lb ^ (r & 7);              // inverse-swizzled source blk
      g2l16(&xb[(size_t)(m0 + r) * 1024 + kt * 128 + sb * 8],
            &Xs[(w * 8 + u) * 512]);
    }
    #pragma unroll
    for (int u = 0; u < 4; ++u) {               // Wt chunk w*4+u
      const int r = (w * 4 + u) * 4 + lr;
      const int sb = lb ^ (r & 7);
      g2l16(&WT[(size_t)(n0 + r) * 1024 + kt * 128 + sb * 8],
            &Wt[(w * 4 + u) * 512]);
    }
    asm volatile("s_waitcnt vmcnt(0)" ::: "memory");
    __syncthreads();                            // staged tile visible
    #pragma unroll
    for (int s = 0; s < 4; ++s) {               // 4 k-steps of 32
      bf16x8 bfr[4];
      #pragma unroll
      for (int ct = 0; ct < 4; ++ct)
        bfr[ct] = *(const bf16x8*)&Wt[(ct * 16 + lm) * 128 +
                                      (((s * 4 + quad) ^ (lm & 7)) << 3)];
      #pragma unroll
      for (int sm = 0; sm < 2; ++sm) {
        const bf16x8 a = *(const bf16x8*)&Xs[(w * 32 + sm * 16 + lm) * 128 +
                                             (((s * 4 + quad) ^ (lm & 7)) << 3)];
        #pragma unroll
        for (int ct = 0; ct < 4; ++ct)
          acc[sm][ct] =
              __builtin_amdgcn_mfma_f32_16x16x32_bf16(a, bfr[ct], acc[sm][ct], 0, 0, 0);
      }
    }
  }

  if (n0 < 1280) {                              // ---- Q or K: RoPE + b64 store
    const bool isQ = n0 < 1024;
    short* outp = isQ ? qo : ko;
    const int base = isQ ? n0 : n0 - 1024;
    const int nh = isQ ? H_ : KH_;
    const int hh = base >> 6;                   // tile width 64 = one head
    const float post = isQ ? QSCALE : 1.0f;     // fold softmax scale into Q
    #pragma unroll
    for (int sm = 0; sm < 2; ++sm)
      #pragma unroll
      for (int r = 0; r < 4; ++r) {
        const int row = m0 + w * 32 + sm * 16 + quad * 4 + r;
        const int b = row >> 11, t = row & 2047;
        float v4[4];
        #pragma unroll
        for (int ct = 0; ct < 4; ++ct) {
          float val = acc[sm][ct][r];
          const float other = __shfl_xor(val, 1);
          const int ci = ct * 16 + lm;          // d within head
          const float2 cs = tbl[t * 32 + (ci >> 1)];
          val = ((ci & 1) == 0) ? (val * cs.x - other * cs.y)
                                : (val * cs.x + other * cs.y);
          v4[ct] = val * post;
        }
        // d ct*16+lm -> slot lm*4+ct: one b64 store of 4 consecutive slots
        uint2 st; st.x = pk2(v4[0], v4[1]); st.y = pk2(v4[2], v4[3]);
        *(uint2*)&outp[((size_t)(b * nh + hh) * T_ + t) * DH_ + lm * 4] = st;
      }
  } else {                                      // ---- V: LDS-bounce transpose
    __syncthreads();                            // done with Xs as GEMM tile
    #pragma unroll
    for (int sm = 0; sm < 2; ++sm)
      #pragma unroll
      for (int r = 0; r < 4; ++r)
        #pragma unroll
        for (int ct = 0; ct < 4; ++ct)
          Xs[(w * 32 + sm * 16 + quad * 4 + r) * 72 + ct * 16 + lm] =
              (short)f2bf(acc[sm][ct][r]);      // Xs[t][d], stride 72 region
    __syncthreads();
    const int kh = (n0 - 1280) >> 6;
    const int b = m0 >> 11, t0 = m0 & 2047;
    short* vb = vt + (size_t)(b * KH_ + kh) * DH_ * T_;
    for (int c = tid; c < 1024; c += 256) {     // 64 d-rows x 16 chunks of 8 slots
      const int d = c >> 4, c8 = (c & 15) * 8;
      short tmp[8];
      #pragma unroll
      for (int j = 0; j < 8; ++j) {
        const int s = c8 + j, sg = s & 63;      // slot s -> token within group
        // tok bits: b5<-g5, b4<-g2, b3:2<-g4:3, b1:0<-g1:0 (in-reg P map)
        const int tok = (s & 64) | (sg & 35) | (((sg >> 2) & 1) << 4) |
                        (((sg >> 3) & 3) << 2);
        tmp[j] = Xs[tok * 72 + d];
      }
      *(bf16x8*)&vb[(size_t)d * T_ + t0 + c8] = *(bf16x8*)tmp;
    }
  }
}

// ---------------------------------------------------------------------------
// Kernel 2: causal flash attention, swapped-QK in-register-P structure.
// sacc = mfma(K,Q) puts q on lane&15 -> softmax + PV A-operand build are
// fully in-lane (16 exp2 + 8 cvt_pk, ZERO cross-lane ops, no P LDS bounce);
// the k-redistribution is absorbed into the V key-slot permutation written
// by kernel 1. LDS = Ks+Vts only = 35840 B -> 4 blocks/CU; launch_bounds
// (256,4) pins VGPR <= 128. Grid 1024 = exactly 4/CU, all resident at t=0;
// qt interleave gives every CU the quad {31-q, q, 31-q, q} = constant 66
// steps (blocks bx, bx+256, bx+512, bx+768 co-locate under both linear
// mod-256 and XCD-major dispatch maps). Diagonal tiles skip ct>w QK-MFMAs
// and 2s>w PV-chunks (wave-uniform). Row-sum via MFMA ones-column;
// register prefetch for K/V; s_setprio(1) around MFMA clusters (T5).
// ---------------------------------------------------------------------------
__global__ __launch_bounds__(256, 4) void attn_mfma_kernel(
    const short* __restrict__ q, const short* __restrict__ k,
    const short* __restrict__ vt, short* __restrict__ att) {
  __shared__ short Ks[128 * 72];
  __shared__ short Vts[64 * 136];               // [d][slot 0..127]

  const int bx = blockIdx.x;
  const int jj = bx & 255, c2 = bx >> 8;
  int qt = (c2 & 1) ? (jj >> 3) : (31 - (jj >> 3));   // heavy-first in chunk 0
  const int hb = (jj & 7) | (c2 << 3);
  const int h = hb >> 1, b = hb & 1;
  const int kh = h >> 2;                        // n_rep = 4
  const int tid = threadIdx.x;
  const int lane = tid & 63, w = tid >> 6;
  const int lm = lane & 15, quad = lane >> 4;
  const int q0 = qt * 64;

  const short* qb = q + (size_t)(b * H_ + h) * T_ * DH_;
  const short* kb = k + (size_t)(b * KH_ + kh) * T_ * DH_;
  const short* vb = vt + (size_t)(b * KH_ + kh) * DH_ * T_;

  bf16x8 ones;
  #pragma unroll
  for (int i = 0; i < 8; ++i) ones[i] = (short)0x3F80;  // bf16 1.0

  bf16x8 aq[2];                                 // kt-invariant Q fragments
  #pragma unroll
  for (int s = 0; s < 2; ++s)                   // direct global load (no LDS)
    aq[s] = *(const bf16x8*)&qb[(size_t)(q0 + w * 16 + lm) * 64 + s * 32 + quad * 8];

  bf16x8 pk[4], pv[4];
  #pragma unroll
  for (int u = 0; u < 4; ++u) {                 // preload r2=0 (128 keys)
    const int c = tid + u * 256;
    const int row = c >> 3, c8 = (c & 7) * 8;
    pk[u] = *(const bf16x8*)&kb[(size_t)row * 64 + c8];
    const int d = c >> 4, c16 = (c & 15) * 8;
    pv[u] = *(const bf16x8*)&vb[(size_t)d * T_ + c16];
  }

  f32x4 oacc[4], lacc;
  #pragma unroll
  for (int i = 0; i < 4; ++i) oacc[i] = (f32x4){0.f, 0.f, 0.f, 0.f};
  lacc = (f32x4){0.f, 0.f, 0.f, 0.f};

  // one 64-key tile-step (j selects which staged half; diag wave-uniform)
  auto step = [&](int j, bool diag) {
    f32x4 sacc[4];
    #pragma unroll
    for (int i = 0; i < 4; ++i) sacc[i] = (f32x4){0.f, 0.f, 0.f, 0.f};
    __builtin_amdgcn_s_setprio(1);
    #pragma unroll
    for (int s2 = 0; s2 < 2; ++s2) {
      #pragma unroll
      for (int ct = 0; ct < 4; ++ct) {
        if (diag && ct > w) continue;           // fully-masked block, skip
        const bf16x8 bb =
            *(const bf16x8*)&Ks[(j * 64 + ct * 16 + lm) * 72 + s2 * 32 + quad * 8];
        // swapped operands: D[key][q], q = lane&15
        sacc[ct] = __builtin_amdgcn_mfma_f32_16x16x32_bf16(bb, aq[s2], sacc[ct], 0, 0, 0);
      }
    }
    __builtin_amdgcn_s_setprio(0);
    // in-lane softmax: sacc[ct][r] = P[key ct*16+quad*4+r][q w*16+lm]
    unsigned int pd[4][2];
    #pragma unroll
    for (int ct = 0; ct < 4; ++ct) {
      float p[4];
      #pragma unroll
      for (int r = 0; r < 4; ++r) {
        float e;
        if (diag && ct > w) e = 0.f;            // block fully above diagonal
        else {
          e = EXP2F(sacc[ct][r]);
          if (diag && ct == w && (quad * 4 + r) > lm) e = 0.f;  // causal mask
        }
        p[r] = e;
      }
      pd[ct][0] = pk2(p[0], p[1]);
      pd[ct][1] = pk2(p[2], p[3]);
    }
    __builtin_amdgcn_s_setprio(1);
    #pragma unroll
    for (int s2 = 0; s2 < 2; ++s2) {
      if (diag && 2 * s2 > w) continue;         // both ct' blocks masked
      union { bf16x8 v; unsigned int u[4]; } pa;
      pa.u[0] = pd[2 * s2][0];     pa.u[1] = pd[2 * s2][1];
      pa.u[2] = pd[2 * s2 + 1][0]; pa.u[3] = pd[2 * s2 + 1][1];
      lacc = __builtin_amdgcn_mfma_f32_16x16x32_bf16(pa.v, ones, lacc, 0, 0, 0);
      #pragma unroll
      for (int ct = 0; ct < 4; ++ct) {
        const bf16x8 vfr = *(const bf16x8*)&Vts[(ct * 16 + lm) * 136 +
                                                j * 64 + s2 * 32 + quad * 8];
        oacc[ct] = __builtin_amdgcn_mfma_f32_16x16x32_bf16(pa.v, vfr, oacc[ct], 0, 0, 0);
      }
    }
    __builtin_amdgcn_s_setprio(0);
  };

  auto stage = [&](int r2) {
    __syncthreads();                            // prior K/V LDS reads done
    #pragma unroll
    for (int u = 0; u < 4; ++u) {
      const int c = tid + u * 256;
      const int row = c >> 3, c8 = (c & 7) * 8;
      *(bf16x8*)&Ks[row * 72 + c8] = pk[u];
      const int d = c >> 4, c16 = (c & 15) * 8;
      *(bf16x8*)&Vts[d * 136 + c16] = pv[u];
    }
    __syncthreads();
    const int r2n = (r2 + 2 <= qt) ? (r2 + 2) : r2;   // prefetch next pair
    #pragma unroll
    for (int u = 0; u < 4; ++u) {
      const int c = tid + u * 256;
      const int row = c >> 3, c8 = (c & 7) * 8;
      pk[u] = *(const bf16x8*)&kb[(size_t)(r2n * 64 + row) * 64 + c8];
      const int d = c >> 4, c16 = (c & 15) * 8;
      pv[u] = *(const bf16x8*)&vb[(size_t)d * T_ + r2n * 64 + c16];
    }
  };

  int r2 = 0;
  for (; r2 + 1 <= qt; r2 += 2) {               // full pairs only
    stage(r2);
    step(0, false);                             // never diagonal
    step(1, r2 + 1 == qt);                      // diagonal only on last pair
  }
  if (r2 == qt) {                               // peeled final step (even qt)
    stage(r2);
    step(0, true);
  }

  #pragma unroll
  for (int r = 0; r < 4; ++r) {
    const int qrow = q0 + w * 16 + quad * 4 + r;
    const float inv = 1.f / lacc[r];
    // d ct*16+lm -> slot lm*4+ct (WoT k-rows match): one b64 store
    uint2 st;
    st.x = pk2(oacc[0][r] * inv, oacc[1][r] * inv);
    st.y = pk2(oacc[2][r] * inv, oacc[3][r] * inv);
    *(uint2*)&att[((size_t)b * T_ + qrow) * 1024 + h * 64 + lm * 4] = st;
  }
}

// ---------------------------------------------------------------------------
// Kernel 3: output projection, 128x64 tiles, BK=128 (8 k-iters), grid
// (32,16) = 512 blocks. Same global_load_lds staging + XOR swizzle as
// kernel 1. bf16 in (slot-permuted k-dim, matched by WoT), fp32 out.
// ---------------------------------------------------------------------------
__global__ __launch_bounds__(256) void outproj_mfma_kernel(
    const short* __restrict__ att, const short* __restrict__ WoT,
    float* __restrict__ out) {
  __shared__ short Xs[128 * 128];
  __shared__ short Wt[64 * 128];
  const int tid = threadIdx.x;
  const int lane = tid & 63, w = tid >> 6;
  const int lm = lane & 15, quad = lane >> 4;
  const int lr = lane >> 4;
  const int lb = lane & 15;
  const int m0 = blockIdx.x * 128;
  const int n0 = blockIdx.y * 64;

  f32x4 acc[2][4];
  #pragma unroll
  for (int sm = 0; sm < 2; ++sm)
    #pragma unroll
    for (int ct = 0; ct < 4; ++ct) acc[sm][ct] = (f32x4){0.f, 0.f, 0.f, 0.f};

  for (int kt = 0; kt < 8; ++kt) {
    __syncthreads();
    #pragma unroll
    for (int u = 0; u < 8; ++u) {
      const int r = (w * 8 + u) * 4 + lr;
      const int sb = lb ^ (r & 7);
      g2l16(&att[(size_t)(m0 + r) * 1024 + kt * 128 + sb * 8],
            &Xs[(w * 8 + u) * 512]);
    }
    #pragma unroll
    for (int u = 0; u < 4; ++u) {
      const int r = (w * 4 + u) * 4 + lr;
      const int sb = lb ^ (r & 7);
      g2l16(&WoT[(size_t)(n0 + r) * 1024 + kt * 128 + sb * 8],
            &Wt[(w * 4 + u) * 512]);
    }
    asm volatile("s_waitcnt vmcnt(0)" ::: "memory");
    __syncthreads();
    #pragma unroll
    for (int s = 0; s < 4; ++s) {
      bf16x8 bfr[4];
      #pragma unroll
      for (int ct = 0; ct < 4; ++ct)
        bfr[ct] = *(const bf16x8*)&Wt[(ct * 16 + lm) * 128 +
                                      (((s * 4 + quad) ^ (lm & 7)) << 3)];
      #pragma unroll
      for (int sm = 0; sm < 2; ++sm) {
        const bf16x8 a = *(const bf16x8*)&Xs[(w * 32 + sm * 16 + lm) * 128 +
                                             (((s * 4 + quad) ^ (lm & 7)) << 3)];
        #pragma unroll
        for (int ct = 0; ct < 4; ++ct)
          acc[sm][ct] =
              __builtin_amdgcn_mfma_f32_16x16x32_bf16(a, bfr[ct], acc[sm][ct], 0, 0, 0);
      }
    }
  }

  #pragma unroll
  for (int sm = 0; sm < 2; ++sm)
    #pragma unroll
    for (int r = 0; r < 4; ++r) {
      const int row = m0 + w * 32 + sm * 16 + quad * 4 + r;
      #pragma unroll
      for (int ct = 0; ct < 4; ++ct)
        out[(size_t)row * 1024 + n0 + ct * 16 + lm] = acc[sm][ct][r];
    }
}

extern "C" void kernel_launch(void* const* d_in, const int* in_sizes, int n_in,
                              void* d_out, int out_size, void* d_ws, size_t ws_size,
                              hipStream_t stream) {
  const float* x  = (const float*)d_in[0];
  // d_in[1] = mask: fixed causal tril, handled analytically; never read.
  const float* Wq = (const float*)d_in[2];
  const float* Wk = (const float*)d_in[3];
  const float* Wv = (const float*)d_in[4];
  const float* Wo = (const float*)d_in[5];
  float* out = (float*)d_out;

  // ws carve (bf16 shorts unless noted): xb 8.4MB | WT 3.1MB | WoT 2.1MB |
  // q 8.4MB | k 2.1MB | vt 2.1MB | att 8.4MB | rope tbl 0.5MB  ~= 35.1MB
  short* xb   = (short*)d_ws;
  short* WT   = xb  + (size_t)4194304;          // 1536*1024
  short* WoT  = WT  + (size_t)1572864;          // 1024*1024 (k sigma-permuted)
  short* qb   = WoT + (size_t)1048576;          // 2*16*2048*64 (d sigma-permuted)
  short* kb   = qb  + (size_t)4194304;          // 2*4*2048*64 (d sigma-permuted)
  short* vtb  = kb  + (size_t)1048576;          // 2*4*64*2048 (transposed+permuted)
  short* attb = vtb + (size_t)1048576;          // 2*2048*1024 (d sigma-permuted)
  float2* tbl = (float2*)(attb + (size_t)4194304);  // 2048*32 float2

  prep_kernel<<<dim3(2944), dim3(256), 0, stream>>>(
      x, Wq, Wk, Wv, Wo, xb, WT, WoT, tbl);
  qkv_mfma_kernel<<<dim3(32, 24), dim3(256), 0, stream>>>(xb, WT, tbl, qb, kb, vtb);
  attn_mfma_kernel<<<dim3(1024), dim3(256), 0, stream>>>(qb, kb, vtb, attb);
  outproj_mfma_kernel<<<dim3(32, 16), dim3(256), 0, stream>>>(attb, WoT, out);
}

// Round 3
// 168.990 us; speedup vs baseline: 1.0345x; 1.0034x over previous
//
#include <hip/hip_runtime.h>
#include <hip/hip_bf16.h>

#define B_  2
#define T_  2048
#define D_  1024
#define H_  16
#define KH_ 4
#define DH_ 64

typedef __attribute__((ext_vector_type(8))) short bf16x8;   // 8 bf16 = 4 VGPRs
typedef __attribute__((ext_vector_type(4))) float f32x4;

// log2(e)/8: folded into Q at projection time so softmax is p = exp2(s_raw).
#define QSCALE 0.18033688011112043f

// single-instruction v_exp_f32 if available (OCML exp2f is ~10 instrs)
#if defined(__has_builtin)
#  if __has_builtin(__builtin_amdgcn_exp2f)
#    define EXP2F(x) __builtin_amdgcn_exp2f(x)
#  endif
#endif
#ifndef EXP2F
#  define EXP2F(x) exp2f(x)
#endif

// fp32 -> bf16 RNE (scalar, for prep paths where cvt_pk doesn't fit)
__device__ __forceinline__ unsigned short f2bf(float f) {
  union { float f; unsigned int u; } v; v.f = f;
  return (unsigned short)((v.u + 0x7FFFu + ((v.u >> 16) & 1u)) >> 16);
}
// packed fp32x2 -> bf16x2 via v_cvt_pk_bf16_f32 (1 VALU op)
__device__ __forceinline__ unsigned int pk2(float a, float b) {
  union { __hip_bfloat162 h2; unsigned int u; } v;
  v.h2 = __float22bfloat162_rn(make_float2(a, b));
  return v.u;
}

// async global->LDS, 16B per lane. LDS dest = wave-uniform base + lane*16;
// global source is per-lane (pre-swizzled source pattern, m173/rule #21).
__device__ __forceinline__ void g2l16(const void* g, void* l) {
  __builtin_amdgcn_global_load_lds(
      (const __attribute__((address_space(1))) void*)g,
      (__attribute__((address_space(3))) void*)l, 16, 0, 0);
}

// d-slot permutation: slot(d) = (d&15)*4 + (d>>4). Applied consistently to
// Q/K d-dims (QK contraction invariant), att per-head d-dim + WoT k-rows
// (outproj contraction invariant). Exact.
//
// V key-slot permutation (attn swapped-QK in-register P): slot g (0..63)
// holds key tok(g) with bit map  tok5<-g5, tok4<-g2, tok3:2<-g4:3,
// tok1:0<-g1:0.  This makes the PV A-operand buildable from each lane's OWN
// exp'd QK outputs (no cross-lane exchange, no P LDS bounce).

// ---------------------------------------------------------------------------
// Merged prep (one launch): x->bf16, Wqkv->WT (bf16 transposed),
// Wo->WoT (bf16 transposed, k-rows sigma-permuted per head), RoPE table.
// ---------------------------------------------------------------------------
__global__ __launch_bounds__(256) void prep_kernel(
    const float* __restrict__ x,  const float* __restrict__ Wq,
    const float* __restrict__ Wk, const float* __restrict__ Wv,
    const float* __restrict__ Wo,
    short* __restrict__ xb, short* __restrict__ WT, short* __restrict__ WoT,
    float2* __restrict__ tbl) {
  __shared__ short Ts[64 * 72];
  const int bid = blockIdx.x, tid = threadIdx.x;

  if (bid < 2048) {                             // ---- x -> bf16
    const size_t i8 = ((size_t)bid * 256 + tid) * 8;
    const float4 a = *(const float4*)&x[i8];
    const float4 b = *(const float4*)&x[i8 + 4];
    uint4 p; p.x = pk2(a.x, a.y); p.y = pk2(a.z, a.w);
    p.z = pk2(b.x, b.y); p.w = pk2(b.z, b.w);
    *(uint4*)&xb[i8] = p;
  } else if (bid < 2688) {                      // ---- WT / WoT transpose
    const bool isW = bid < 2432;
    const int idx = isW ? (bid - 2048) : (bid - 2432);
    const int n0 = (idx >> 4) * 64, k0 = (idx & 15) * 64;
    const float* src; int ncols, c0; short* dst;
    if (isW) {
      dst = WT;
      if (n0 < 1024)      { src = Wq; ncols = 1024; c0 = n0; }
      else if (n0 < 1280) { src = Wk; ncols = 256;  c0 = n0 - 1024; }
      else                { src = Wv; ncols = 256;  c0 = n0 - 1280; }
    } else { dst = WoT; src = Wo; ncols = 1024; c0 = n0; }
    for (int i = tid; i < 1024; i += 256) {
      const int kr = i >> 4, c4 = (i & 15) << 2;
      // WoT k-rows permuted: slot(kr) = (kr&15)*4 + (kr>>4) (k0 is 64-aligned
      // = one head's range, so per-head sigma).
      const int kc = isW ? kr : ((kr & 15) * 4 + (kr >> 4));
      const float4 w = *(const float4*)&src[(size_t)(k0 + kr) * ncols + c0 + c4];
      Ts[(c4 + 0) * 72 + kc] = (short)f2bf(w.x);
      Ts[(c4 + 1) * 72 + kc] = (short)f2bf(w.y);
      Ts[(c4 + 2) * 72 + kc] = (short)f2bf(w.z);
      Ts[(c4 + 3) * 72 + kc] = (short)f2bf(w.w);
    }
    __syncthreads();
    for (int c = tid; c < 512; c += 256) {
      const int nr = c >> 3, c8 = (c & 7) * 8;
      *(bf16x8*)&dst[(size_t)(n0 + nr) * 1024 + k0 + c8] =
          *(const bf16x8*)&Ts[nr * 72 + c8];
    }
  } else {                                      // ---- RoPE table
    const int e = (bid - 2688) * 256 + tid;     // 65536 entries
    const int t = e >> 5, i2 = e & 31;
    const float freq = exp2f(-(float)(2 * i2) * (18.931568569324174f / 64.0f));
    float sn, cs; sincosf((float)t * freq, &sn, &cs);
    tbl[e] = make_float2(cs, sn);
  }
}

// ---------------------------------------------------------------------------
// Kernel 1: QKV projection, 128x64 tiles, BK=128 (8 k-iters, 32 MFMA per
// barrier-pair per wave), grid 768 1-D blocks (3/CU).
// XCD-chunked mapping (T1, strengthened): xcd = bid&7 (round-robin dispatch
// assumption, m157); each XCD owns m-tiles [xcd*4, xcd*4+4) x ALL 24
// n-tiles. Per-XCD L2 working set: A 4x256KB + B panels ~3MB ~= 4MB = fits
// (was ~24MB: every A-tile refetched from L3 per n-block, ~200MB/launch).
// Staging via global_load_lds width=16 (m97 pattern). LDS linear stride 128
// with XOR block swizzle (source-side pre-swizzle, rule #21).
// nt<16: Q (RoPE + QSCALE fold). 16..19: K (RoPE). 20..23: V (LDS-bounce
// transpose -> (b,kh,d,t), key slots permuted per attn's in-register-P map).
// ---------------------------------------------------------------------------
__global__ __launch_bounds__(256) void qkv_mfma_kernel(
    const short* __restrict__ xb, const short* __restrict__ WT,
    const float2* __restrict__ tbl,
    short* __restrict__ qo, short* __restrict__ ko, short* __restrict__ vt) {
  __shared__ short Xs[128 * 128];
  __shared__ short Wt[64 * 128];
  const int tid = threadIdx.x;
  const int lane = tid & 63, w = tid >> 6;
  const int lm = lane & 15, quad = lane >> 4;
  const int lr = lane >> 4;                     // row within 4-row LDS chunk
  const int lb = lane & 15;                     // dest 16B block within row
  // XCD-chunked decode: 768 = 8 XCDs x (4 m x 24 n)
  const int bid = blockIdx.x;
  const int xcd = bid & 7, slot = bid >> 3;     // slot 0..95
  const int mt = xcd * 4 + (slot & 3);          // 0..31
  const int nt = slot >> 2;                     // 0..23
  const int m0 = mt * 128;
  const int n0 = nt * 64;                       // 0..1472

  f32x4 acc[2][4];
  #pragma unroll
  for (int sm = 0; sm < 2; ++sm)
    #pragma unroll
    for (int ct = 0; ct < 4; ++ct) acc[sm][ct] = (f32x4){0.f, 0.f, 0.f, 0.f};

  for (int kt = 0; kt < 8; ++kt) {
    __syncthreads();                            // prior tile's LDS reads done
    #pragma unroll
    for (int u = 0; u < 8; ++u) {               // Xs chunk w*8+u (4 rows/1KB)
      const int r = (w * 8 + u) * 4 + lr;
      const int sb = lb ^ (r & 7);              // inverse-swizzled source blk
      g2l16(&xb[(size_t)(m0 + r) * 1024 + kt * 128 + sb * 8],
            &Xs[(w * 8 + u) * 512]);
    }
    #pragma unroll
    for (int u = 0; u < 4; ++u) {               // Wt chunk w*4+u
      const int r = (w * 4 + u) * 4 + lr;
      const int sb = lb ^ (r & 7);
      g2l16(&WT[(size_t)(n0 + r) * 1024 + kt * 128 + sb * 8],
            &Wt[(w * 4 + u) * 512]);
    }
    asm volatile("s_waitcnt vmcnt(0)" ::: "memory");
    __syncthreads();                            // staged tile visible
    #pragma unroll
    for (int s = 0; s < 4; ++s) {               // 4 k-steps of 32
      bf16x8 bfr[4];
      #pragma unroll
      for (int ct = 0; ct < 4; ++ct)
        bfr[ct] = *(const bf16x8*)&Wt[(ct * 16 + lm) * 128 +
                                      (((s * 4 + quad) ^ (lm & 7)) << 3)];
      #pragma unroll
      for (int sm = 0; sm < 2; ++sm) {
        const bf16x8 a = *(const bf16x8*)&Xs[(w * 32 + sm * 16 + lm) * 128 +
                                             (((s * 4 + quad) ^ (lm & 7)) << 3)];
        #pragma unroll
        for (int ct = 0; ct < 4; ++ct)
          acc[sm][ct] =
              __builtin_amdgcn_mfma_f32_16x16x32_bf16(a, bfr[ct], acc[sm][ct], 0, 0, 0);
      }
    }
  }

  if (n0 < 1280) {                              // ---- Q or K: RoPE + b64 store
    const bool isQ = n0 < 1024;
    short* outp = isQ ? qo : ko;
    const int base = isQ ? n0 : n0 - 1024;
    const int nh = isQ ? H_ : KH_;
    const int hh = base >> 6;                   // tile width 64 = one head
    const float post = isQ ? QSCALE : 1.0f;     // fold softmax scale into Q
    #pragma unroll
    for (int sm = 0; sm < 2; ++sm)
      #pragma unroll
      for (int r = 0; r < 4; ++r) {
        const int row = m0 + w * 32 + sm * 16 + quad * 4 + r;
        const int b = row >> 11, t = row & 2047;
        float v4[4];
        #pragma unroll
        for (int ct = 0; ct < 4; ++ct) {
          float val = acc[sm][ct][r];
          const float other = __shfl_xor(val, 1);
          const int ci = ct * 16 + lm;          // d within head
          const float2 cs = tbl[t * 32 + (ci >> 1)];
          val = ((ci & 1) == 0) ? (val * cs.x - other * cs.y)
                                : (val * cs.x + other * cs.y);
          v4[ct] = val * post;
        }
        // d ct*16+lm -> slot lm*4+ct: one b64 store of 4 consecutive slots
        uint2 st; st.x = pk2(v4[0], v4[1]); st.y = pk2(v4[2], v4[3]);
        *(uint2*)&outp[((size_t)(b * nh + hh) * T_ + t) * DH_ + lm * 4] = st;
      }
  } else {                                      // ---- V: LDS-bounce transpose
    __syncthreads();                            // done with Xs as GEMM tile
    #pragma unroll
    for (int sm = 0; sm < 2; ++sm)
      #pragma unroll
      for (int r = 0; r < 4; ++r)
        #pragma unroll
        for (int ct = 0; ct < 4; ++ct)
          Xs[(w * 32 + sm * 16 + quad * 4 + r) * 72 + ct * 16 + lm] =
              (short)f2bf(acc[sm][ct][r]);      // Xs[t][d], stride 72 region
    __syncthreads();
    const int kh = (n0 - 1280) >> 6;
    const int b = m0 >> 11, t0 = m0 & 2047;
    short* vb = vt + (size_t)(b * KH_ + kh) * DH_ * T_;
    for (int c = tid; c < 1024; c += 256) {     // 64 d-rows x 16 chunks of 8 slots
      const int d = c >> 4, c8 = (c & 15) * 8;
      short tmp[8];
      #pragma unroll
      for (int j = 0; j < 8; ++j) {
        const int s = c8 + j, sg = s & 63;      // slot s -> token within group
        // tok bits: b5<-g5, b4<-g2, b3:2<-g4:3, b1:0<-g1:0 (in-reg P map)
        const int tok = (s & 64) | (sg & 35) | (((sg >> 2) & 1) << 4) |
                        (((sg >> 3) & 3) << 2);
        tmp[j] = Xs[tok * 72 + d];
      }
      *(bf16x8*)&vb[(size_t)d * T_ + t0 + c8] = *(bf16x8*)tmp;
    }
  }
}

// ---------------------------------------------------------------------------
// Kernel 2: causal flash attention, swapped-QK in-register-P structure.
// sacc = mfma(K,Q) puts q on lane&15 -> softmax + PV A-operand build are
// fully in-lane (16 exp2 + 8 cvt_pk, ZERO cross-lane ops, no P LDS bounce);
// the k-redistribution is absorbed into the V key-slot permutation written
// by kernel 1. LDS = Ks+Vts only = 35840 B -> 4 blocks/CU; launch_bounds
// (256,4) pins VGPR <= 128. Grid 1024 = exactly 4/CU, all resident at t=0;
// qt interleave gives every CU the quad {31-q, q, 31-q, q} = constant 66
// steps. Diagonal tiles skip ct>w QK-MFMAs and 2s>w PV-chunks
// (wave-uniform). Row-sum via MFMA ones-column; register prefetch for K/V;
// s_setprio(1) around MFMA clusters (T5). [UNCHANGED from round 2]
// ---------------------------------------------------------------------------
__global__ __launch_bounds__(256, 4) void attn_mfma_kernel(
    const short* __restrict__ q, const short* __restrict__ k,
    const short* __restrict__ vt, short* __restrict__ att) {
  __shared__ short Ks[128 * 72];
  __shared__ short Vts[64 * 136];               // [d][slot 0..127]

  const int bx = blockIdx.x;
  const int jj = bx & 255, c2 = bx >> 8;
  int qt = (c2 & 1) ? (jj >> 3) : (31 - (jj >> 3));   // heavy-first in chunk 0
  const int hb = (jj & 7) | (c2 << 3);
  const int h = hb >> 1, b = hb & 1;
  const int kh = h >> 2;                        // n_rep = 4
  const int tid = threadIdx.x;
  const int lane = tid & 63, w = tid >> 6;
  const int lm = lane & 15, quad = lane >> 4;
  const int q0 = qt * 64;

  const short* qb = q + (size_t)(b * H_ + h) * T_ * DH_;
  const short* kb = k + (size_t)(b * KH_ + kh) * T_ * DH_;
  const short* vb = vt + (size_t)(b * KH_ + kh) * DH_ * T_;

  bf16x8 ones;
  #pragma unroll
  for (int i = 0; i < 8; ++i) ones[i] = (short)0x3F80;  // bf16 1.0

  bf16x8 aq[2];                                 // kt-invariant Q fragments
  #pragma unroll
  for (int s = 0; s < 2; ++s)                   // direct global load (no LDS)
    aq[s] = *(const bf16x8*)&qb[(size_t)(q0 + w * 16 + lm) * 64 + s * 32 + quad * 8];

  bf16x8 pk[4], pv[4];
  #pragma unroll
  for (int u = 0; u < 4; ++u) {                 // preload r2=0 (128 keys)
    const int c = tid + u * 256;
    const int row = c >> 3, c8 = (c & 7) * 8;
    pk[u] = *(const bf16x8*)&kb[(size_t)row * 64 + c8];
    const int d = c >> 4, c16 = (c & 15) * 8;
    pv[u] = *(const bf16x8*)&vb[(size_t)d * T_ + c16];
  }

  f32x4 oacc[4], lacc;
  #pragma unroll
  for (int i = 0; i < 4; ++i) oacc[i] = (f32x4){0.f, 0.f, 0.f, 0.f};
  lacc = (f32x4){0.f, 0.f, 0.f, 0.f};

  // one 64-key tile-step (j selects which staged half; diag wave-uniform)
  auto step = [&](int j, bool diag) {
    f32x4 sacc[4];
    #pragma unroll
    for (int i = 0; i < 4; ++i) sacc[i] = (f32x4){0.f, 0.f, 0.f, 0.f};
    __builtin_amdgcn_s_setprio(1);
    #pragma unroll
    for (int s2 = 0; s2 < 2; ++s2) {
      #pragma unroll
      for (int ct = 0; ct < 4; ++ct) {
        if (diag && ct > w) continue;           // fully-masked block, skip
        const bf16x8 bb =
            *(const bf16x8*)&Ks[(j * 64 + ct * 16 + lm) * 72 + s2 * 32 + quad * 8];
        // swapped operands: D[key][q], q = lane&15
        sacc[ct] = __builtin_amdgcn_mfma_f32_16x16x32_bf16(bb, aq[s2], sacc[ct], 0, 0, 0);
      }
    }
    __builtin_amdgcn_s_setprio(0);
    // in-lane softmax: sacc[ct][r] = P[key ct*16+quad*4+r][q w*16+lm]
    unsigned int pd[4][2];
    #pragma unroll
    for (int ct = 0; ct < 4; ++ct) {
      float p[4];
      #pragma unroll
      for (int r = 0; r < 4; ++r) {
        float e;
        if (diag && ct > w) e = 0.f;            // block fully above diagonal
        else {
          e = EXP2F(sacc[ct][r]);
          if (diag && ct == w && (quad * 4 + r) > lm) e = 0.f;  // causal mask
        }
        p[r] = e;
      }
      pd[ct][0] = pk2(p[0], p[1]);
      pd[ct][1] = pk2(p[2], p[3]);
    }
    __builtin_amdgcn_s_setprio(1);
    #pragma unroll
    for (int s2 = 0; s2 < 2; ++s2) {
      if (diag && 2 * s2 > w) continue;         // both ct' blocks masked
      union { bf16x8 v; unsigned int u[4]; } pa;
      pa.u[0] = pd[2 * s2][0];     pa.u[1] = pd[2 * s2][1];
      pa.u[2] = pd[2 * s2 + 1][0]; pa.u[3] = pd[2 * s2 + 1][1];
      lacc = __builtin_amdgcn_mfma_f32_16x16x32_bf16(pa.v, ones, lacc, 0, 0, 0);
      #pragma unroll
      for (int ct = 0; ct < 4; ++ct) {
        const bf16x8 vfr = *(const bf16x8*)&Vts[(ct * 16 + lm) * 136 +
                                                j * 64 + s2 * 32 + quad * 8];
        oacc[ct] = __builtin_amdgcn_mfma_f32_16x16x32_bf16(pa.v, vfr, oacc[ct], 0, 0, 0);
      }
    }
    __builtin_amdgcn_s_setprio(0);
  };

  auto stage = [&](int r2) {
    __syncthreads();                            // prior K/V LDS reads done
    #pragma unroll
    for (int u = 0; u < 4; ++u) {
      const int c = tid + u * 256;
      const int row = c >> 3, c8 = (c & 7) * 8;
      *(bf16x8*)&Ks[row * 72 + c8] = pk[u];
      const int d = c >> 4, c16 = (c & 15) * 8;
      *(bf16x8*)&Vts[d * 136 + c16] = pv[u];
    }
    __syncthreads();
    const int r2n = (r2 + 2 <= qt) ? (r2 + 2) : r2;   // prefetch next pair
    #pragma unroll
    for (int u = 0; u < 4; ++u) {
      const int c = tid + u * 256;
      const int row = c >> 3, c8 = (c & 7) * 8;
      pk[u] = *(const bf16x8*)&kb[(size_t)(r2n * 64 + row) * 64 + c8];
      const int d = c >> 4, c16 = (c & 15) * 8;
      pv[u] = *(const bf16x8*)&vb[(size_t)d * T_ + r2n * 64 + c16];
    }
  };

  int r2 = 0;
  for (; r2 + 1 <= qt; r2 += 2) {               // full pairs only
    stage(r2);
    step(0, false);                             // never diagonal
    step(1, r2 + 1 == qt);                      // diagonal only on last pair
  }
  if (r2 == qt) {                               // peeled final step (even qt)
    stage(r2);
    step(0, true);
  }

  #pragma unroll
  for (int r = 0; r < 4; ++r) {
    const int qrow = q0 + w * 16 + quad * 4 + r;
    const float inv = 1.f / lacc[r];
    // d ct*16+lm -> slot lm*4+ct (WoT k-rows match): one b64 store
    uint2 st;
    st.x = pk2(oacc[0][r] * inv, oacc[1][r] * inv);
    st.y = pk2(oacc[2][r] * inv, oacc[3][r] * inv);
    *(uint2*)&att[((size_t)b * T_ + qrow) * 1024 + h * 64 + lm * 4] = st;
  }
}

// ---------------------------------------------------------------------------
// Kernel 3: output projection, 128x64 tiles, BK=128 (8 k-iters), grid 512
// 1-D blocks. XCD-chunked mapping: xcd = bid&7 owns m-tiles [xcd*4,
// xcd*4+4) x ALL 16 n-tiles -> per-XCD L2 working set A 1MB + WoT 2MB =
// fits (was ~16MB). Same global_load_lds staging + XOR swizzle as kernel 1.
// bf16 in (slot-permuted k-dim, matched by WoT), fp32 out.
// ---------------------------------------------------------------------------
__global__ __launch_bounds__(256) void outproj_mfma_kernel(
    const short* __restrict__ att, const short* __restrict__ WoT,
    float* __restrict__ out) {
  __shared__ short Xs[128 * 128];
  __shared__ short Wt[64 * 128];
  const int tid = threadIdx.x;
  const int lane = tid & 63, w = tid >> 6;
  const int lm = lane & 15, quad = lane >> 4;
  const int lr = lane >> 4;
  const int lb = lane & 15;
  // XCD-chunked decode: 512 = 8 XCDs x (4 m x 16 n)
  const int bid = blockIdx.x;
  const int xcd = bid & 7, slot = bid >> 3;     // slot 0..63
  const int m0 = (xcd * 4 + (slot & 3)) * 128;
  const int n0 = (slot >> 2) * 64;              // 0..960

  f32x4 acc[2][4];
  #pragma unroll
  for (int sm = 0; sm < 2; ++sm)
    #pragma unroll
    for (int ct = 0; ct < 4; ++ct) acc[sm][ct] = (f32x4){0.f, 0.f, 0.f, 0.f};

  for (int kt = 0; kt < 8; ++kt) {
    __syncthreads();
    #pragma unroll
    for (int u = 0; u < 8; ++u) {
      const int r = (w * 8 + u) * 4 + lr;
      const int sb = lb ^ (r & 7);
      g2l16(&att[(size_t)(m0 + r) * 1024 + kt * 128 + sb * 8],
            &Xs[(w * 8 + u) * 512]);
    }
    #pragma unroll
    for (int u = 0; u < 4; ++u) {
      const int r = (w * 4 + u) * 4 + lr;
      const int sb = lb ^ (r & 7);
      g2l16(&WoT[(size_t)(n0 + r) * 1024 + kt * 128 + sb * 8],
            &Wt[(w * 4 + u) * 512]);
    }
    asm volatile("s_waitcnt vmcnt(0)" ::: "memory");
    __syncthreads();
    #pragma unroll
    for (int s = 0; s < 4; ++s) {
      bf16x8 bfr[4];
      #pragma unroll
      for (int ct = 0; ct < 4; ++ct)
        bfr[ct] = *(const bf16x8*)&Wt[(ct * 16 + lm) * 128 +
                                      (((s * 4 + quad) ^ (lm & 7)) << 3)];
      #pragma unroll
      for (int sm = 0; sm < 2; ++sm) {
        const bf16x8 a = *(const bf16x8*)&Xs[(w * 32 + sm * 16 + lm) * 128 +
                                             (((s * 4 + quad) ^ (lm & 7)) << 3)];
        #pragma unroll
        for (int ct = 0; ct < 4; ++ct)
          acc[sm][ct] =
              __builtin_amdgcn_mfma_f32_16x16x32_bf16(a, bfr[ct], acc[sm][ct], 0, 0, 0);
      }
    }
  }

  #pragma unroll
  for (int sm = 0; sm < 2; ++sm)
    #pragma unroll
    for (int r = 0; r < 4; ++r) {
      const int row = m0 + w * 32 + sm * 16 + quad * 4 + r;
      #pragma unroll
      for (int ct = 0; ct < 4; ++ct)
        out[(size_t)row * 1024 + n0 + ct * 16 + lm] = acc[sm][ct][r];
    }
}

extern "C" void kernel_launch(void* const* d_in, const int* in_sizes, int n_in,
                              void* d_out, int out_size, void* d_ws, size_t ws_size,
                              hipStream_t stream) {
  const float* x  = (const float*)d_in[0];
  // d_in[1] = mask: fixed causal tril, handled analytically; never read.
  const float* Wq = (const float*)d_in[2];
  const float* Wk = (const float*)d_in[3];
  const float* Wv = (const float*)d_in[4];
  const float* Wo = (const float*)d_in[5];
  float* out = (float*)d_out;

  // ws carve (bf16 shorts unless noted): xb 8.4MB | WT 3.1MB | WoT 2.1MB |
  // q 8.4MB | k 2.1MB | vt 2.1MB | att 8.4MB | rope tbl 0.5MB  ~= 35.1MB
  short* xb   = (short*)d_ws;
  short* WT   = xb  + (size_t)4194304;          // 1536*1024
  short* WoT  = WT  + (size_t)1572864;          // 1024*1024 (k sigma-permuted)
  short* qb   = WoT + (size_t)1048576;          // 2*16*2048*64 (d sigma-permuted)
  short* kb   = qb  + (size_t)4194304;          // 2*4*2048*64 (d sigma-permuted)
  short* vtb  = kb  + (size_t)1048576;          // 2*4*64*2048 (transposed+permuted)
  short* attb = vtb + (size_t)1048576;          // 2*2048*1024 (d sigma-permuted)
  float2* tbl = (float2*)(attb + (size_t)4194304);  // 2048*32 float2

  prep_kernel<<<dim3(2944), dim3(256), 0, stream>>>(
      x, Wq, Wk, Wv, Wo, xb, WT, WoT, tbl);
  qkv_mfma_kernel<<<dim3(768), dim3(256), 0, stream>>>(xb, WT, tbl, qb, kb, vtb);
  attn_mfma_kernel<<<dim3(1024), dim3(256), 0, stream>>>(qb, kb, vtb, attb);
  outproj_mfma_kernel<<<dim3(512), dim3(256), 0, stream>>>(attb, WoT, out);
}